// Round 2
// baseline (389.852 us; speedup 1.0000x reference)
//
#include <hip/hip_runtime.h>
#include <hip/hip_bf16.h>

// Problem constants (fixed by setup_inputs):
//   B=4, N_down=16384, N_up=65536, C_down=256, C_up=128, C_out=128
// I/O dtypes per the reference: all float tensors fp32, up_idx int32, out fp32.
// Compute path: fp32 -> bf16 (on-the-fly cvt) -> MFMA (fp32 accum) -> fp32 out.
constexpr int N_DOWN = 16384;
constexpr int N_UP   = 65536;
constexpr int BATCH  = 4;
constexpr int M_BLK  = 64;            // rows per block
constexpr int LDS_STRIDE = 136;       // 128 + 8 pad (bf16): 272B/row, 16B-aligned rows

typedef __attribute__((ext_vector_type(8))) short short8;   // 8 x bf16 — MFMA A/B frag
typedef __attribute__((ext_vector_type(4))) float f32x4;    // MFMA C/D frag

__device__ inline short f2bs(float f) {
  __hip_bfloat16 h = __float2bfloat16(f);
  return __builtin_bit_cast(short, h);
}

// Load 8 consecutive fp32 and convert to a bf16 A/B fragment (two float4 loads).
__device__ inline short8 load_cvt8(const float* __restrict__ p) {
  float4 lo = *(const float4*)p;
  float4 hi = *(const float4*)(p + 4);
  short8 r;
  r[0] = f2bs(lo.x); r[1] = f2bs(lo.y); r[2] = f2bs(lo.z); r[3] = f2bs(lo.w);
  r[4] = f2bs(hi.x); r[5] = f2bs(hi.y); r[6] = f2bs(hi.z); r[7] = f2bs(hi.w);
  return r;
}

// ---------------------------------------------------------------------------
// Repack W_lin / W_fus ([K=256][N=128] row-major fp32) into bf16 MFMA
// B-fragment order: chunk t = w*4096 + kk*512 + strip*64 + lane holds
//   val[j] = W[kk*32 + (lane>>4)*8 + j][strip*16 + (lane&15)]
// so the main kernel loads each B-frag as ONE contiguous 16B load.
// ---------------------------------------------------------------------------
__global__ void repack_w(const float* __restrict__ Wl,
                         const float* __restrict__ Wf,
                         __hip_bfloat16* __restrict__ pack) {
  int t = blockIdx.x * 256 + threadIdx.x;          // 0 .. 8191
  if (t >= 8192) return;
  int lane  = t & 63;
  int strip = (t >> 6) & 7;
  int kk    = (t >> 9) & 7;
  int w     = t >> 12;
  const float* W = w ? Wf : Wl;
  int q = lane >> 4;
  int l = lane & 15;
  int c = strip * 16 + l;
  short8 vals;
#pragma unroll
  for (int j = 0; j < 8; ++j) {
    int k = kk * 32 + q * 8 + j;
    vals[j] = f2bs(W[k * 128 + c]);
  }
  *(short8*)(pack + (size_t)t * 8) = vals;
}

// ---------------------------------------------------------------------------
// Fused: gather -> GEMM1(256->128)+bias+leaky -> concat -> GEMM2(256->128)
//        +bias+leaky -> out.
// Block: 512 threads = 8 waves, 64 rows/block.
//   wave = rg (row group, 16 rows) + cg (col group, 64 cols = 4 strips of 16).
// GEMM1 A-frags stream straight from global via the gather (x_down rows are
// 1KB contiguous fp32; 67MB total -> LLC-resident on re-reads).
// GEMM1 result -> LDS (C-layout scatter, bf16), re-read in A-layout for
// GEMM2's upper K half; GEMM2's lower K half reads x_up from global.
// ---------------------------------------------------------------------------
__global__ __launch_bounds__(512, 4)
void fused_up(const float* __restrict__ x_down,
              const float* __restrict__ x_up,
              const int* __restrict__ up_idx,
              const float* __restrict__ b_lin,
              const float* __restrict__ b_fus,
              const __hip_bfloat16* __restrict__ pack,
              float* __restrict__ out) {
  __shared__ __hip_bfloat16 x_lin_lds[M_BLK * LDS_STRIDE];

  const int tid  = threadIdx.x;
  const int wave = tid >> 6;
  const int lane = tid & 63;
  const int rg   = wave & 3;        // row group: rows rg*16 .. rg*16+15
  const int cg   = wave >> 2;       // col group: cols cg*64 .. cg*64+63
  const int q    = lane >> 4;       // quad id (k-slice for A/B frags)
  const int l    = lane & 15;       // row (A) / col (B,C) within 16-tile

  const int m0 = blockIdx.x * M_BLK;       // flat row base over B*N_up
  const int b  = m0 >> 16;                 // / N_UP
  const int r0 = rg * 16;
  const int m  = m0 + r0 + l;              // this lane's logical row

  const int row_idx = up_idx[m];           // gather index (L1-broadcast across quads)
  const float* a1_base =
      x_down + ((size_t)b * N_DOWN + (size_t)row_idx) * 256 + q * 8;

  // ---------------- GEMM1: x_g[64x256] @ W_lin[256x128] ----------------
  f32x4 acc[4];
#pragma unroll
  for (int s = 0; s < 4; ++s) acc[s] = f32x4{0.f, 0.f, 0.f, 0.f};

#pragma unroll
  for (int kk = 0; kk < 8; ++kk) {
    short8 a = load_cvt8(a1_base + kk * 32);
#pragma unroll
    for (int s = 0; s < 4; ++s) {
      int strip = cg * 4 + s;
      short8 bf = *(const short8*)(pack + (size_t)((kk * 8 + strip) * 64 + lane) * 8);
      acc[s] = __builtin_amdgcn_mfma_f32_16x16x32_bf16(a, bf, acc[s], 0, 0, 0);
    }
  }

  // epilogue 1: bias + leaky-relu, C-layout scatter into LDS (bf16)
#pragma unroll
  for (int s = 0; s < 4; ++s) {
    int c = cg * 64 + s * 16 + l;
    float bias = b_lin[c];
#pragma unroll
    for (int i = 0; i < 4; ++i) {
      float v = acc[s][i] + bias;
      v = (v >= 0.f) ? v : 0.1f * v;
      int r = r0 + q * 4 + i;
      x_lin_lds[r * LDS_STRIDE + c] = __float2bfloat16(v);
    }
  }
  __syncthreads();

  // ---------------- GEMM2: [x_up | x_lin][64x256] @ W_fus[256x128] ------
  const float* a2_base = x_up + (size_t)m * 128 + q * 8;

  f32x4 acc2[4];
#pragma unroll
  for (int s = 0; s < 4; ++s) acc2[s] = f32x4{0.f, 0.f, 0.f, 0.f};

#pragma unroll
  for (int kk = 0; kk < 8; ++kk) {
    short8 a;
    if (kk < 4) {
      a = load_cvt8(a2_base + kk * 32);                              // x_up half (fp32)
    } else {
      a = *(const short8*)(&x_lin_lds[(r0 + l) * LDS_STRIDE + (kk - 4) * 32 + q * 8]);
    }
#pragma unroll
    for (int s = 0; s < 4; ++s) {
      int strip = cg * 4 + s;
      short8 bf = *(const short8*)(pack + (size_t)(4096 + (kk * 8 + strip) * 64 + lane) * 8);
      acc2[s] = __builtin_amdgcn_mfma_f32_16x16x32_bf16(a, bf, acc2[s], 0, 0, 0);
    }
  }

  // epilogue 2: bias + leaky-relu, fp32 store (16 lanes -> 64B contiguous runs)
#pragma unroll
  for (int s = 0; s < 4; ++s) {
    int c = cg * 64 + s * 16 + l;
    float bias = b_fus[c];
#pragma unroll
    for (int i = 0; i < 4; ++i) {
      float v = acc2[s][i] + bias;
      v = (v >= 0.f) ? v : 0.1f * v;
      size_t r = (size_t)(m0 + r0 + q * 4 + i);
      out[r * 128 + c] = v;
    }
  }
}

extern "C" void kernel_launch(void* const* d_in, const int* in_sizes, int n_in,
                              void* d_out, int out_size, void* d_ws, size_t ws_size,
                              hipStream_t stream) {
  const float* x_down = (const float*)d_in[0];
  const float* x_up   = (const float*)d_in[1];
  const int*   up_idx = (const int*)d_in[2];
  const float* W_lin  = (const float*)d_in[3];
  const float* b_lin  = (const float*)d_in[4];
  const float* W_fus  = (const float*)d_in[5];
  const float* b_fus  = (const float*)d_in[6];
  float* out = (float*)d_out;
  __hip_bfloat16* pack = (__hip_bfloat16*)d_ws;   // 128 KiB used

  repack_w<<<32, 256, 0, stream>>>(W_lin, W_fus, pack);
  fused_up<<<(BATCH * N_UP) / M_BLK, 512, 0, stream>>>(
      x_down, x_up, up_idx, b_lin, b_fus, pack, out);
}

// Round 3
// 305.567 us; speedup vs baseline: 1.2758x; 1.2758x over previous
//
#include <hip/hip_runtime.h>
#include <hip/hip_bf16.h>

// Problem constants (fixed by setup_inputs):
//   B=4, N_down=16384, N_up=65536, C_down=256, C_up=128, C_out=128
// I/O: fp32 tensors, int32 idx, fp32 out. Compute: bf16 MFMA, fp32 accum.
constexpr int N_DOWN = 16384;
constexpr int N_UP   = 65536;
constexpr int BATCH  = 4;
constexpr int M_BLK  = 64;     // rows per block
constexpr int A1S    = 264;    // LDS row stride (bf16) for gathered x_down tile (256+8 pad; 528B = 16B-aligned, banks balanced)
constexpr int A2S    = 264;    // LDS row stride for concat [x_up | x_lin] tile

typedef __attribute__((ext_vector_type(8))) short short8;   // 8 x bf16 MFMA A/B frag
typedef __attribute__((ext_vector_type(4))) float f32x4;    // MFMA C/D frag

static __device__ inline unsigned short f2b(float f) {
  __hip_bfloat16 h = __float2bfloat16(f);
  return __builtin_bit_cast(unsigned short, h);
}
// fp32x4 -> bf16x4, single 8B LDS store
static __device__ inline void cvt_store4(__hip_bfloat16* dst, float4 v) {
  ushort4 s;
  s.x = f2b(v.x); s.y = f2b(v.y); s.z = f2b(v.z); s.w = f2b(v.w);
  *(ushort4*)dst = s;
}

// ---------------------------------------------------------------------------
// Repack W_lin / W_fus ([K=256][N=128] row-major fp32) into bf16 MFMA
// B-fragment order: chunk t = w*4096 + kk*512 + strip*64 + lane holds
//   val[j] = W[kk*32 + (lane>>4)*8 + j][strip*16 + (lane&15)]
// so each B-frag is ONE contiguous 16B load in the main kernel.
// ---------------------------------------------------------------------------
__global__ void repack_w(const float* __restrict__ Wl,
                         const float* __restrict__ Wf,
                         __hip_bfloat16* __restrict__ pack) {
  int t = blockIdx.x * 256 + threadIdx.x;          // 0 .. 8191
  if (t >= 8192) return;
  int lane  = t & 63;
  int strip = (t >> 6) & 7;
  int kk    = (t >> 9) & 7;
  int w     = t >> 12;
  const float* W = w ? Wf : Wl;
  int q = lane >> 4;
  int l = lane & 15;
  int c = strip * 16 + l;
  short8 vals;
#pragma unroll
  for (int j = 0; j < 8; ++j) {
    int k = kk * 32 + q * 8 + j;
    vals[j] = (short)f2b(W[k * 128 + c]);
  }
  *(short8*)(pack + (size_t)t * 8) = vals;
}

// ---------------------------------------------------------------------------
// Fused gather -> MLP1 -> concat -> MLP2.
// Block: 512 threads = 8 waves, 64 rows. Wave w owns ALL 64 rows x cols
// [w*16, w*16+16): its 8 B-frags per GEMM stay register-resident.
// Stage 1 (coalesced, cvt to bf16): gathered x_down rows -> LDS A1[64][264],
//   x_up rows -> LDS A2[64][264] cols 0..127.
// GEMM1: A from LDS (ds_read_b128), B from regs -> epilogue writes x_lin
//   (bias+leaky, bf16) into A2 cols 128..255 (the concat).
// GEMM2: A from LDS A2, B2 regs -> bias+leaky -> fp32 out.
// ---------------------------------------------------------------------------
__global__ __launch_bounds__(512, 4)
void fused_up(const float* __restrict__ x_down,
              const float* __restrict__ x_up,
              const int* __restrict__ up_idx,
              const float* __restrict__ b_lin,
              const float* __restrict__ b_fus,
              const __hip_bfloat16* __restrict__ pack,
              float* __restrict__ out) {
  __shared__ __hip_bfloat16 A1[M_BLK * A1S];
  __shared__ __hip_bfloat16 A2[M_BLK * A2S];

  const int tid  = threadIdx.x;
  const int wave = tid >> 6;        // col strip: cols wave*16 .. wave*16+15
  const int lane = tid & 63;
  const int q    = lane >> 4;       // quad (k-slice / C row group)
  const int l    = lane & 15;       // col within strip (B,C) / row (A)

  const int m0 = blockIdx.x * M_BLK;      // flat row base over B*N_up
  const int b  = m0 >> 16;                // / N_UP

  // ---- stage gathered x_down rows -> A1 (fully coalesced: 8 lanes x 16B
  //      cover one 128B line of a row; fp32 -> bf16 on the fly) ----
  {
    const int lr = tid >> 3;              // local row 0..63
    const int s8 = tid & 7;
    const int gi = up_idx[m0 + lr];       // 8 threads share one idx -> broadcast
    const float* src = x_down + ((size_t)b * N_DOWN + (size_t)gi) * 256;
    __hip_bfloat16* dst = A1 + lr * A1S;
#pragma unroll
    for (int j = 0; j < 8; ++j) {
      int c4 = j * 8 + s8;                // float4 col; lanes contiguous per j
      float4 v = *(const float4*)(src + c4 * 4);
      cvt_store4(dst + c4 * 4, v);
    }
  }
  // ---- stage x_up rows (contiguous block) -> A2 cols 0..127 ----
  {
#pragma unroll
    for (int j = 0; j < 4; ++j) {
      int f  = j * 512 + tid;             // 0..2047 float4s, fully coalesced
      int r  = f >> 5;                    // 32 float4 per row
      int c4 = f & 31;
      float4 v = *(const float4*)(x_up + (size_t)(m0 + r) * 128 + c4 * 4);
      cvt_store4(A2 + r * A2S + c4 * 4, v);
    }
  }

  // ---- B1 frags: loaded ONCE, register-resident (32 VGPRs) ----
  short8 B1[8];
#pragma unroll
  for (int kk = 0; kk < 8; ++kk)
    B1[kk] = *(const short8*)(pack + (size_t)((kk * 8 + wave) * 64 + lane) * 8);

  const float bias1 = b_lin[wave * 16 + l];
  const float bias2 = b_fus[wave * 16 + l];

  __syncthreads();

  // ---- GEMM1: [64x256] @ W_lin[:, wave strip] ----
  f32x4 acc[4];
#pragma unroll
  for (int rg = 0; rg < 4; ++rg) acc[rg] = f32x4{0.f, 0.f, 0.f, 0.f};
#pragma unroll
  for (int kk = 0; kk < 8; ++kk) {
#pragma unroll
    for (int rg = 0; rg < 4; ++rg) {
      short8 a = *(const short8*)(A1 + (rg * 16 + l) * A1S + kk * 32 + q * 8);
      acc[rg] = __builtin_amdgcn_mfma_f32_16x16x32_bf16(a, B1[kk], acc[rg], 0, 0, 0);
    }
  }

  // ---- B2 frags (issued here; latency overlaps epilogue + barrier) ----
  short8 B2[8];
#pragma unroll
  for (int kk = 0; kk < 8; ++kk)
    B2[kk] = *(const short8*)(pack + (size_t)(4096 + (kk * 8 + wave) * 64 + lane) * 8);

  // ---- epilogue1: bias + leaky -> bf16 -> A2 cols 128..255 (concat) ----
#pragma unroll
  for (int rg = 0; rg < 4; ++rg) {
#pragma unroll
    for (int i = 0; i < 4; ++i) {
      float v = acc[rg][i] + bias1;
      v = (v >= 0.f) ? v : 0.1f * v;
      A2[(rg * 16 + q * 4 + i) * A2S + 128 + wave * 16 + l] = __float2bfloat16(v);
    }
  }
  __syncthreads();

  // ---- GEMM2: concat[64x256] @ W_fus[:, wave strip] ----
  f32x4 acc2[4];
#pragma unroll
  for (int rg = 0; rg < 4; ++rg) acc2[rg] = f32x4{0.f, 0.f, 0.f, 0.f};
#pragma unroll
  for (int kk = 0; kk < 8; ++kk) {
#pragma unroll
    for (int rg = 0; rg < 4; ++rg) {
      short8 a = *(const short8*)(A2 + (rg * 16 + l) * A2S + kk * 32 + q * 8);
      acc2[rg] = __builtin_amdgcn_mfma_f32_16x16x32_bf16(a, B2[kk], acc2[rg], 0, 0, 0);
    }
  }

  // ---- epilogue2: bias + leaky -> fp32 out (16 lanes = 64B runs) ----
#pragma unroll
  for (int rg = 0; rg < 4; ++rg) {
#pragma unroll
    for (int i = 0; i < 4; ++i) {
      float v = acc2[rg][i] + bias2;
      v = (v >= 0.f) ? v : 0.1f * v;
      out[(size_t)(m0 + rg * 16 + q * 4 + i) * 128 + wave * 16 + l] = v;
    }
  }
}

extern "C" void kernel_launch(void* const* d_in, const int* in_sizes, int n_in,
                              void* d_out, int out_size, void* d_ws, size_t ws_size,
                              hipStream_t stream) {
  const float* x_down = (const float*)d_in[0];
  const float* x_up   = (const float*)d_in[1];
  const int*   up_idx = (const int*)d_in[2];
  const float* W_lin  = (const float*)d_in[3];
  const float* b_lin  = (const float*)d_in[4];
  const float* W_fus  = (const float*)d_in[5];
  const float* b_fus  = (const float*)d_in[6];
  float* out = (float*)d_out;
  __hip_bfloat16* pack = (__hip_bfloat16*)d_ws;   // 128 KiB used

  repack_w<<<32, 256, 0, stream>>>(W_lin, W_fus, pack);
  fused_up<<<(BATCH * N_UP) / M_BLK, 512, 0, stream>>>(
      x_down, x_up, up_idx, b_lin, b_fus, pack, out);
}

// Round 4
// 302.045 us; speedup vs baseline: 1.2907x; 1.0117x over previous
//
#include <hip/hip_runtime.h>
#include <hip/hip_bf16.h>

// Problem constants (fixed by setup_inputs):
//   B=4, N_down=16384, N_up=65536, C_down=256, C_up=128, C_out=128
// I/O: fp32 tensors, int32 idx, fp32 out. Compute: bf16 MFMA, fp32 accum.
constexpr int N_DOWN = 16384;
constexpr int N_UP   = 65536;
constexpr int BATCH  = 4;
constexpr int M_BLK  = 64;     // rows per block
constexpr int TS     = 264;    // LDS row stride (bf16): 256+8 pad, 528B rows (16B-aligned)

typedef __attribute__((ext_vector_type(8))) short short8;   // 8 x bf16 MFMA A/B frag
typedef __attribute__((ext_vector_type(4))) float f32x4;    // MFMA C/D frag

static __device__ inline unsigned short f2b(float f) {
  __hip_bfloat16 h = __float2bfloat16(f);
  return __builtin_bit_cast(unsigned short, h);
}
// fp32x4 -> bf16x4, single 8B LDS store
static __device__ inline void cvt_store4(__hip_bfloat16* dst, float4 v) {
  ushort4 s;
  s.x = f2b(v.x); s.y = f2b(v.y); s.z = f2b(v.z); s.w = f2b(v.w);
  *(ushort4*)dst = s;
}

// ---------------------------------------------------------------------------
// Repack W_lin / W_fus ([K=256][N=128] row-major fp32) into bf16 MFMA
// B-fragment order: chunk t = w*4096 + kk*512 + strip*64 + lane holds
//   val[j] = W[kk*32 + (lane>>4)*8 + j][strip*16 + (lane&15)]
// so each B-frag is ONE contiguous 16B load in the main kernel.
// ---------------------------------------------------------------------------
__global__ void repack_w(const float* __restrict__ Wl,
                         const float* __restrict__ Wf,
                         __hip_bfloat16* __restrict__ pack) {
  int t = blockIdx.x * 256 + threadIdx.x;          // 0 .. 8191
  if (t >= 8192) return;
  int lane  = t & 63;
  int strip = (t >> 6) & 7;
  int kk    = (t >> 9) & 7;
  int w     = t >> 12;
  const float* W = w ? Wf : Wl;
  int q = lane >> 4;
  int l = lane & 15;
  int c = strip * 16 + l;
  short8 vals;
#pragma unroll
  for (int j = 0; j < 8; ++j) {
    int k = kk * 32 + q * 8 + j;
    vals[j] = (short)f2b(W[k * 128 + c]);
  }
  *(short8*)(pack + (size_t)t * 8) = vals;
}

// ---------------------------------------------------------------------------
// Fused gather -> MLP1 -> concat -> MLP2 with a SINGLE 64x264 LDS tile
// (33.8 KB -> 3-4 blocks/CU vs 2 at 66KB; phase overlap across blocks).
// Phases: [prefetch x_up to regs + stage gathered x_down -> T + load B1]
//   sync -> GEMM1 (A from T) -> sync (T free) ->
//   [x_up regs -> T cols 0..127; epilogue1 x_lin -> T cols 128..255; load B2]
//   sync -> GEMM2 -> bias+leaky -> fp32 out.
// Wave w owns all 64 rows x cols [w*16, w*16+16): B-frags register-resident.
// ---------------------------------------------------------------------------
__global__ __launch_bounds__(512, 6)
void fused_up(const float* __restrict__ x_down,
              const float* __restrict__ x_up,
              const int* __restrict__ up_idx,
              const float* __restrict__ b_lin,
              const float* __restrict__ b_fus,
              const __hip_bfloat16* __restrict__ pack,
              float* __restrict__ out) {
  __shared__ __hip_bfloat16 T[M_BLK * TS];

  const int tid  = threadIdx.x;
  const int wave = tid >> 6;        // col strip: cols wave*16 .. wave*16+15
  const int lane = tid & 63;
  const int q    = lane >> 4;       // quad (k-slice / C row group)
  const int l    = lane & 15;       // col within strip (B,C) / row (A)

  const int m0 = blockIdx.x * M_BLK;      // flat row base over B*N_up
  const int b  = m0 >> 16;                // / N_UP

  // ---- prefetch x_up rows into registers (coalesced float4); latency
  //      overlaps staging + GEMM1 ----
  float4 xup[4];
#pragma unroll
  for (int j = 0; j < 4; ++j) {
    int f = j * 512 + tid;                // 0..2047 float4s
    int r = f >> 5;                       // 32 float4 per row
    int c4 = f & 31;
    xup[j] = *(const float4*)(x_up + (size_t)(m0 + r) * 128 + c4 * 4);
  }

  // ---- stage gathered x_down rows -> T (coalesced: 8 lanes x 16B per
  //      128B line; fp32 -> bf16 on the fly) ----
  {
    const int lr = tid >> 3;              // local row 0..63
    const int s8 = tid & 7;
    const int gi = up_idx[m0 + lr];       // 8 threads share one idx
    const float* src = x_down + ((size_t)b * N_DOWN + (size_t)gi) * 256;
    __hip_bfloat16* dst = T + lr * TS;
#pragma unroll
    for (int j = 0; j < 8; ++j) {
      int c4 = j * 8 + s8;
      float4 v = *(const float4*)(src + c4 * 4);
      cvt_store4(dst + c4 * 4, v);
    }
  }

  // ---- B1 frags: loaded ONCE, register-resident ----
  short8 B1[8];
#pragma unroll
  for (int kk = 0; kk < 8; ++kk)
    B1[kk] = *(const short8*)(pack + (size_t)((kk * 8 + wave) * 64 + lane) * 8);

  const float bias1 = b_lin[wave * 16 + l];
  const float bias2 = b_fus[wave * 16 + l];

  __syncthreads();

  // ---- GEMM1: gathered[64x256] @ W_lin[:, wave strip] ----
  f32x4 acc[4];
#pragma unroll
  for (int rg = 0; rg < 4; ++rg) acc[rg] = f32x4{0.f, 0.f, 0.f, 0.f};
#pragma unroll
  for (int kk = 0; kk < 8; ++kk) {
#pragma unroll
    for (int rg = 0; rg < 4; ++rg) {
      short8 a = *(const short8*)(T + (rg * 16 + l) * TS + kk * 32 + q * 8);
      acc[rg] = __builtin_amdgcn_mfma_f32_16x16x32_bf16(a, B1[kk], acc[rg], 0, 0, 0);
    }
  }
  __syncthreads();   // all waves done reading T; safe to overwrite

  // ---- phase 2: build concat tile in T ----
  // x_up (from regs) -> cols 0..127
#pragma unroll
  for (int j = 0; j < 4; ++j) {
    int f = j * 512 + tid;
    int r = f >> 5;
    int c4 = f & 31;
    cvt_store4(T + r * TS + c4 * 4, xup[j]);
  }
  // x_lin (epilogue1: bias + leaky) -> cols 128..255
#pragma unroll
  for (int rg = 0; rg < 4; ++rg) {
#pragma unroll
    for (int i = 0; i < 4; ++i) {
      float v = acc[rg][i] + bias1;
      v = (v >= 0.f) ? v : 0.1f * v;
      T[(rg * 16 + q * 4 + i) * TS + 128 + wave * 16 + l] = __float2bfloat16(v);
    }
  }
  // B2 frags (L1-hot after first block on the CU)
  short8 B2[8];
#pragma unroll
  for (int kk = 0; kk < 8; ++kk)
    B2[kk] = *(const short8*)(pack + (size_t)(4096 + (kk * 8 + wave) * 64 + lane) * 8);

  __syncthreads();

  // ---- GEMM2: concat[64x256] @ W_fus[:, wave strip] ----
  f32x4 acc2[4];
#pragma unroll
  for (int rg = 0; rg < 4; ++rg) acc2[rg] = f32x4{0.f, 0.f, 0.f, 0.f};
#pragma unroll
  for (int kk = 0; kk < 8; ++kk) {
#pragma unroll
    for (int rg = 0; rg < 4; ++rg) {
      short8 a = *(const short8*)(T + (rg * 16 + l) * TS + kk * 32 + q * 8);
      acc2[rg] = __builtin_amdgcn_mfma_f32_16x16x32_bf16(a, B2[kk], acc2[rg], 0, 0, 0);
    }
  }

  // ---- epilogue2: bias + leaky -> fp32 out (16 lanes = 64B runs) ----
#pragma unroll
  for (int rg = 0; rg < 4; ++rg) {
#pragma unroll
    for (int i = 0; i < 4; ++i) {
      float v = acc2[rg][i] + bias2;
      v = (v >= 0.f) ? v : 0.1f * v;
      out[(size_t)(m0 + rg * 16 + q * 4 + i) * 128 + wave * 16 + l] = v;
    }
  }
}

extern "C" void kernel_launch(void* const* d_in, const int* in_sizes, int n_in,
                              void* d_out, int out_size, void* d_ws, size_t ws_size,
                              hipStream_t stream) {
  const float* x_down = (const float*)d_in[0];
  const float* x_up   = (const float*)d_in[1];
  const int*   up_idx = (const int*)d_in[2];
  const float* W_lin  = (const float*)d_in[3];
  const float* b_lin  = (const float*)d_in[4];
  const float* W_fus  = (const float*)d_in[5];
  const float* b_fus  = (const float*)d_in[6];
  float* out = (float*)d_out;
  __hip_bfloat16* pack = (__hip_bfloat16*)d_ws;   // 128 KiB used

  repack_w<<<32, 256, 0, stream>>>(W_lin, W_fus, pack);
  fused_up<<<(BATCH * N_UP) / M_BLK, 512, 0, stream>>>(
      x_down, x_up, up_idx, b_lin, b_fus, pack, out);
}